// Round 1
// baseline (353.403 us; speedup 1.0000x reference)
//
#include <hip/hip_runtime.h>

typedef unsigned short u16;
typedef unsigned int   u32;
typedef __attribute__((ext_vector_type(4))) float f32x4;
typedef __attribute__((ext_vector_type(4))) u32   u32x4;
typedef __attribute__((ext_vector_type(4))) u16   u16x4;
typedef __attribute__((ext_vector_type(8))) short bf16x8;

#define NN 4096
#define CC 256
#define CQ 32

// round-to-nearest-even f32 -> bf16 bits (inputs are finite)
__device__ __forceinline__ u16 f2bf(float x) {
  union { float f; u32 u; } c; c.f = x;
  u32 r = c.u + 0x7FFFu + ((c.u >> 16) & 1u);
  return (u16)(r >> 16);
}

__device__ __forceinline__ f32x4 mfma16(u32x4 a, u32x4 b, f32x4 c) {
  return __builtin_amdgcn_mfma_f32_16x16x32_bf16(
      __builtin_bit_cast(bf16x8, a), __builtin_bit_cast(bf16x8, b), c, 0, 0, 0);
}

// ---------------------------------------------------------------------------
// Kernel 1: 1x1-conv projections, fp32 vector math, bf16 outputs.
//   chunk 0: q = (Wq.F3 + bq) * (log2e/sqrt(32)) -> qT[b][n][32]
//   chunk 1: k = (Wk.F1 + bk)                    -> kT[b][n][32]
//   chunk 2..9: v = (Wv.F2 + bv) rows 32*(chunk-2).. -> v[b][c][n]
// thread <-> n (coalesced x loads); W rows are wave-uniform -> s_loads.
// ---------------------------------------------------------------------------
__global__ __launch_bounds__(256) void proj_kernel(
    const float* __restrict__ F3, const float* __restrict__ F1, const float* __restrict__ F2,
    const float* __restrict__ Wq, const float* __restrict__ bq,
    const float* __restrict__ Wk, const float* __restrict__ bk,
    const float* __restrict__ Wv, const float* __restrict__ bv,
    u16* __restrict__ qT, u16* __restrict__ kT, u16* __restrict__ vO) {
  const int n = blockIdx.x * 256 + threadIdx.x;
  const int b = blockIdx.y;
  const int chunk = blockIdx.z;
  const float* X; const float* W; const float* bias; int c0;
  if (chunk == 0)      { X = F3; W = Wq; bias = bq; c0 = 0; }
  else if (chunk == 1) { X = F1; W = Wk; bias = bk; c0 = 0; }
  else                 { X = F2; W = Wv; bias = bv; c0 = (chunk - 2) * 32; }

  const float* xcol = X + (size_t)b * CC * NN + n;
  float acc[32];
#pragma unroll
  for (int j = 0; j < 32; ++j) acc[j] = 0.f;

  for (int cc = 0; cc < CC; ++cc) {
    const float x = xcol[(size_t)cc * NN];
    const float* wrow = W + c0 * CC + cc;
#pragma unroll
    for (int j = 0; j < 32; ++j) acc[j] = fmaf(wrow[j * CC], x, acc[j]);
  }

  if (chunk <= 1) {
    // fold softmax scale AND log2(e) into q so attention works in exp2 domain
    const float qsc = (chunk == 0) ? (1.4426950408889634f / 5.656854249492380f) : 1.0f;
    u16 tmp[32];
#pragma unroll
    for (int j = 0; j < 32; ++j) tmp[j] = f2bf((acc[j] + bias[j]) * qsc);
    u16* dst = (chunk == 0 ? qT : kT) + ((size_t)b * NN + n) * CQ;
#pragma unroll
    for (int t = 0; t < 4; ++t)
      *(u32x4*)(dst + t * 8) = *(const u32x4*)(tmp + t * 8);
  } else {
#pragma unroll
    for (int j = 0; j < 32; ++j)
      vO[((size_t)b * CC + c0 + j) * NN + n] = f2bf(acc[j] + bias[c0 + j]);
  }
}

// ---------------------------------------------------------------------------
// Kernel 2: fused flash attention + epilogue (gamma*out + F3).
// Block: 256 thr = 4 waves. Block tile: 64 n x 128 c (c-split=2 across blocks).
// Wave w: softmax owner of n-slice [n0+16w, +16); PV owner of 32 c's.
// Per 64-m step: E = mfma(K,Q) swapped (D[m][n]), wave-parallel online
// softmax (shfl_xor 16/32), P -> XOR-swizzled LDS (double-buffered, ONE
// barrier/step), then rescale + 16 PV mfmas (A=v from global/L2, B=P from LDS).
// XCD swizzle: bid%8 -> XCD; batch b pinned to XCDs {2b,2b+1}; c-half per XCD
// so v-half (1MB) + k + q stay L2-resident.
// ---------------------------------------------------------------------------
__global__ __launch_bounds__(256, 2) void attn_kernel(
    const u16* __restrict__ qT, const u16* __restrict__ kT, const u16* __restrict__ vV,
    const float* __restrict__ F3, const float* __restrict__ gamma,
    float* __restrict__ out) {
  __shared__ u16   pT[2][64][64];
  __shared__ float corrS[2][64];
  __shared__ float lrowS[64];

  const int bid = blockIdx.x;
  const int b   = (bid & 7) >> 1;
  const int idx = ((bid >> 3) << 1) | (bid & 1);   // 0..127 within batch
  const int n0  = (idx >> 1) * 64;
  const int c0b = (idx & 1) * 128;

  const int tid  = threadIdx.x;
  const int w    = tid >> 6;
  const int lane = tid & 63;
  const int r15  = lane & 15;
  const int g    = lane >> 4;
  const int swz  = (r15 & 7) << 3;   // XOR swizzle on LDS elem index bits 3..5

  // Q fragment, held all kernel: B-operand, cols n = n0+16w+r15, k-chunk 8g
  const u32x4 qf = *(const u32x4*)(qT + ((size_t)b * NN + (n0 + 16 * w + r15)) * CQ + 8 * g);

  const u16* kbase = kT + ((size_t)b * NN + r15) * CQ + 8 * g;        // + m*CQ
  const int  c0w   = c0b + 32 * w;
  const u16* vbase = vV + ((size_t)b * CC + c0w + r15) * NN + 8 * g;  // + cs*16*NN + m

  float mrun = -INFINITY, lrun = 0.f;
  f32x4 acc[2][4];
#pragma unroll
  for (int cs = 0; cs < 2; ++cs)
#pragma unroll
    for (int ns = 0; ns < 4; ++ns) acc[cs][ns] = f32x4{0.f, 0.f, 0.f, 0.f};

  for (int t = 0; t < 64; ++t) {
    const int m0  = t * 64;
    const int buf = t & 1;

    // ---- energy tiles: D[m-local][n-local], m-local = 16s+4g+r, n = r15
    f32x4 ef[4];
#pragma unroll
    for (int s = 0; s < 4; ++s) {
      const u32x4 kf = *(const u32x4*)(kbase + (size_t)(m0 + 16 * s) * CQ);
      ef[s] = mfma16(kf, qf, f32x4{0.f, 0.f, 0.f, 0.f});
    }

    // ---- online softmax (exp2 domain; scale prefolded into q)
    float tmax = -INFINITY;
#pragma unroll
    for (int s = 0; s < 4; ++s)
#pragma unroll
      for (int r = 0; r < 4; ++r) tmax = fmaxf(tmax, ef[s][r]);
    tmax = fmaxf(tmax, __shfl_xor(tmax, 16));
    tmax = fmaxf(tmax, __shfl_xor(tmax, 32));
    const float newm = fmaxf(mrun, tmax);
    const float corr = exp2f(mrun - newm);   // exp2(-inf)=0 on first tile
    float psum = 0.f;
    const int prow = 16 * w + r15;
#pragma unroll
    for (int s = 0; s < 4; ++s) {
      const float p0 = exp2f(ef[s][0] - newm);
      const float p1 = exp2f(ef[s][1] - newm);
      const float p2 = exp2f(ef[s][2] - newm);
      const float p3 = exp2f(ef[s][3] - newm);
      psum += (p0 + p1) + (p2 + p3);
      u16x4 pk = {f2bf(p0), f2bf(p1), f2bf(p2), f2bf(p3)};
      *(u16x4*)&pT[buf][prow][(16 * s + 4 * g) ^ swz] = pk;
    }
    psum += __shfl_xor(psum, 16);
    psum += __shfl_xor(psum, 32);
    lrun = lrun * corr + psum;
    mrun = newm;
    if (lane < 16) corrS[buf][16 * w + lane] = corr;
    __syncthreads();   // P complete; prev-step readers done with buf^1

    // ---- rescale accumulators by this step's correction (per accum-n)
    float cf[4];
#pragma unroll
    for (int ns = 0; ns < 4; ++ns) cf[ns] = corrS[buf][16 * ns + r15];
#pragma unroll
    for (int cs = 0; cs < 2; ++cs)
#pragma unroll
      for (int ns = 0; ns < 4; ++ns) {
        acc[cs][ns][0] *= cf[ns]; acc[cs][ns][1] *= cf[ns];
        acc[cs][ns][2] *= cf[ns]; acc[cs][ns][3] *= cf[ns];
      }

    // ---- PV: acc[c-tile][n-tile] += v(A) x P(B), K=32 per mfma
#pragma unroll
    for (int kc = 0; kc < 2; ++kc) {
      u32x4 pf[4];
#pragma unroll
      for (int ns = 0; ns < 4; ++ns)
        pf[ns] = *(const u32x4*)&pT[buf][16 * ns + r15][(32 * kc + 8 * g) ^ swz];
#pragma unroll
      for (int cs = 0; cs < 2; ++cs) {
        const u32x4 vf = *(const u32x4*)(vbase + (size_t)cs * 16 * NN + m0 + 32 * kc);
#pragma unroll
        for (int ns = 0; ns < 4; ++ns)
          acc[cs][ns] = mfma16(vf, pf[ns], acc[cs][ns]);
      }
    }
    // no second barrier: next step writes pT[buf^1] (double-buffered)
  }

  // ---- epilogue: out = gamma * acc/l + F3
  if (lane < 16) lrowS[16 * w + lane] = lrun;
  __syncthreads();
  const float gam = gamma[0];
#pragma unroll
  for (int ns = 0; ns < 4; ++ns) {
    const float inv = 1.f / lrowS[16 * ns + r15];
    const int n = n0 + 16 * ns + r15;
#pragma unroll
    for (int cs = 0; cs < 2; ++cs)
#pragma unroll
      for (int r = 0; r < 4; ++r) {
        const int c = c0w + 16 * cs + 4 * g + r;
        const size_t o = ((size_t)b * CC + c) * NN + n;
        out[o] = fmaf(gam * inv, acc[cs][ns][r], F3[o]);
      }
  }
}

extern "C" void kernel_launch(void* const* d_in, const int* in_sizes, int n_in,
                              void* d_out, int out_size, void* d_ws, size_t ws_size,
                              hipStream_t stream) {
  const float* F3 = (const float*)d_in[0];
  const float* F1 = (const float*)d_in[1];
  const float* F2 = (const float*)d_in[2];
  const float* Wq = (const float*)d_in[3];
  const float* bq = (const float*)d_in[4];
  const float* Wk = (const float*)d_in[5];
  const float* bk = (const float*)d_in[6];
  const float* Wv = (const float*)d_in[7];
  const float* bv = (const float*)d_in[8];
  const float* gm = (const float*)d_in[9];
  float* out = (float*)d_out;

  // workspace: qT (1MB) | kT (1MB) | v (8MB), all bf16  -- needs 10MB of ws
  u16* qT = (u16*)d_ws;
  u16* kT = qT + (size_t)4 * NN * CQ;
  u16* vW = kT + (size_t)4 * NN * CQ;

  proj_kernel<<<dim3(16, 4, 10), 256, 0, stream>>>(F3, F1, F2, Wq, bq, Wk, bk, Wv, bv, qT, kT, vW);
  attn_kernel<<<512, 256, 0, stream>>>(qT, kT, vW, F3, gm, out);
}

// Round 2
// 273.694 us; speedup vs baseline: 1.2912x; 1.2912x over previous
//
#include <hip/hip_runtime.h>

typedef unsigned short u16;
typedef unsigned int   u32;
typedef __attribute__((ext_vector_type(2))) u32   u32x2;
typedef __attribute__((ext_vector_type(4))) float f32x4;
typedef __attribute__((ext_vector_type(4))) u32   u32x4;
typedef __attribute__((ext_vector_type(8))) short bf16x8;

#define NN 4096
#define CC 256
#define CQ 32

// round-to-nearest-even f32 -> bf16 bits (scalar path)
__device__ __forceinline__ u16 f2bf(float x) {
  union { float f; u32 u; } c; c.f = x;
  u32 r = c.u + 0x7FFFu + ((c.u >> 16) & 1u);
  return (u16)(r >> 16);
}

// packed f32 pair -> 2x bf16 (RNE), single VALU op
__device__ __forceinline__ u32 cvt_pk(float lo, float hi) {
  u32 r;
  asm("v_cvt_pk_bf16_f32 %0, %1, %2" : "=v"(r) : "v"(lo), "v"(hi));
  return r;
}

// raw v_exp_f32 (exp2), avoids OCML denormal-fixup ops
#if __has_builtin(__builtin_amdgcn_exp2f)
__device__ __forceinline__ float exp2a(float x) { return __builtin_amdgcn_exp2f(x); }
#else
__device__ __forceinline__ float exp2a(float x) { return exp2f(x); }
#endif

__device__ __forceinline__ float fmax3(float a, float b, float c) {
  return fmaxf(fmaxf(a, b), c);   // clang fuses to v_max3_f32
}

__device__ __forceinline__ f32x4 mfma16(u32x4 a, u32x4 b, f32x4 c) {
  return __builtin_amdgcn_mfma_f32_16x16x32_bf16(
      __builtin_bit_cast(bf16x8, a), __builtin_bit_cast(bf16x8, b), c, 0, 0, 0);
}

// ---------------------------------------------------------------------------
// Kernel 1: 1x1-conv projections. Block = 64-n tile x one 32-row j-chunk.
// X tile [256c][64n] staged to LDS once (f32, +2 pad); 256 thr = 64 n x 4 jg.
// W loads are wave-uniform (jg readfirstlane'd) -> s_load_dwordx4.
// acc[8] scalars -> no spill possible.
//   z=0: q=(Wq.F3+bq)*log2e/sqrt(32) -> qT[b][n][32]  (bf16)
//   z=1: k= Wk.F1+bk                 -> kT[b][n][32]  (bf16)
//   z>1: v= Wv.F2+bv rows 32(z-2)..  -> v[b][c][n]    (bf16)
// ---------------------------------------------------------------------------
__global__ __launch_bounds__(256) void proj_kernel(
    const float* __restrict__ F3, const float* __restrict__ F1, const float* __restrict__ F2,
    const float* __restrict__ Wq, const float* __restrict__ bq,
    const float* __restrict__ Wk, const float* __restrict__ bk,
    const float* __restrict__ Wv, const float* __restrict__ bv,
    u16* __restrict__ qT, u16* __restrict__ kT, u16* __restrict__ vO) {
  __shared__ float xs[256][66];
  const int n0 = blockIdx.x * 64;
  const int b  = blockIdx.y;
  const int z  = blockIdx.z;
  const float* X; const float* W; const float* bias;
  if (z == 0)      { X = F3; W = Wq; bias = bq; }
  else if (z == 1) { X = F1; W = Wk; bias = bk; }
  else             { X = F2; W = Wv; bias = bv; }

  const int tid = threadIdx.x;
  const float* Xb = X + (size_t)b * CC * NN + n0;
#pragma unroll
  for (int i = 0; i < 16; ++i) {
    const int cid = i * 256 + tid;
    const int row = cid >> 4, col = (cid & 15) * 4;
    f32x4 v = *(const f32x4*)(Xb + (size_t)row * NN + col);
    *(f32x4*)&xs[row][col] = v;
  }
  __syncthreads();

  const int n  = tid & 63;
  const int jg = __builtin_amdgcn_readfirstlane(tid >> 6);
  const int jb = (z <= 1 ? 0 : (z - 2) * 32) + jg * 8;  // absolute out-row base
  const float* Wb = W + (size_t)jb * CC;

  float acc[8] = {0.f, 0.f, 0.f, 0.f, 0.f, 0.f, 0.f, 0.f};
#pragma unroll 2
  for (int c4 = 0; c4 < 64; ++c4) {
    const float x0 = xs[4 * c4 + 0][n];
    const float x1 = xs[4 * c4 + 1][n];
    const float x2 = xs[4 * c4 + 2][n];
    const float x3 = xs[4 * c4 + 3][n];
#pragma unroll
    for (int jj = 0; jj < 8; ++jj) {
      const f32x4 wv = *(const f32x4*)(Wb + jj * CC + 4 * c4);
      acc[jj] = fmaf(wv[0], x0, acc[jj]);
      acc[jj] = fmaf(wv[1], x1, acc[jj]);
      acc[jj] = fmaf(wv[2], x2, acc[jj]);
      acc[jj] = fmaf(wv[3], x3, acc[jj]);
    }
  }

  if (z <= 1) {
    const float qsc = (z == 0) ? (1.4426950408889634f / 5.656854249492380f) : 1.0f;
    float r[8];
#pragma unroll
    for (int jj = 0; jj < 8; ++jj) r[jj] = (acc[jj] + bias[jb + jj]) * qsc;
    u32x4 o;
    o[0] = cvt_pk(r[0], r[1]); o[1] = cvt_pk(r[2], r[3]);
    o[2] = cvt_pk(r[4], r[5]); o[3] = cvt_pk(r[6], r[7]);
    u16* dst = (z == 0 ? qT : kT) + ((size_t)b * NN + n0 + n) * CQ + jg * 8;
    *(u32x4*)dst = o;
  } else {
#pragma unroll
    for (int jj = 0; jj < 8; ++jj) {
      const float r = acc[jj] + bias[jb + jj];
      vO[((size_t)b * CC + jb + jj) * NN + n0 + n] = f2bf(r);
    }
  }
}

// ---------------------------------------------------------------------------
// Kernel 2: fused flash attention + epilogue (gamma*out + F3).
// 256 thr = 4 waves; block tile 64n x 128c (c-split 2). One barrier/step,
// double-buffered P in LDS (XOR swizzle). K-frag double-buffer + V-frag
// hoist hide L2 latency under softmax. Softmax in exp2 domain (scale folded
// into q), raw v_exp, cvt_pk bf16 packing, defer-rescale when max static.
// ---------------------------------------------------------------------------
__global__ __launch_bounds__(256, 2) void attn_kernel(
    const u16* __restrict__ qT, const u16* __restrict__ kT, const u16* __restrict__ vV,
    const float* __restrict__ F3, const float* __restrict__ gamma,
    float* __restrict__ out) {
  __shared__ u16   pT[2][64][64];
  __shared__ float corrS[2][64];
  __shared__ float lrowS[64];

  const int bid = blockIdx.x;
  const int b   = (bid & 7) >> 1;
  const int idx = ((bid >> 3) << 1) | (bid & 1);   // 0..127 within batch
  const int n0  = (idx >> 1) * 64;
  const int c0b = (idx & 1) * 128;

  const int tid  = threadIdx.x;
  const int w    = tid >> 6;
  const int lane = tid & 63;
  const int r15  = lane & 15;
  const int g    = lane >> 4;
  const int swz  = (r15 & 7) << 3;

  const u32x4 qf = *(const u32x4*)(qT + ((size_t)b * NN + (n0 + 16 * w + r15)) * CQ + 8 * g);

  const u16* kbase = kT + ((size_t)b * NN + r15) * CQ + 8 * g;
  const int  c0w   = c0b + 32 * w;
  const u16* vbase = vV + ((size_t)b * CC + c0w + r15) * NN + 8 * g;

  u32x4 kf[4];
#pragma unroll
  for (int s = 0; s < 4; ++s) kf[s] = *(const u32x4*)(kbase + (size_t)(16 * s) * CQ);

  float mrun = -INFINITY, lrun = 0.f;
  f32x4 acc[2][4];
#pragma unroll
  for (int cs = 0; cs < 2; ++cs)
#pragma unroll
    for (int ns = 0; ns < 4; ++ns) acc[cs][ns] = f32x4{0.f, 0.f, 0.f, 0.f};

  const int prow = 16 * w + r15;

  for (int t = 0; t < 64; ++t) {
    const int m0  = t * 64;
    const int buf = t & 1;

    // ---- energy: D[m][n], m-local = 16s+4g+r, n = n0+16w+r15
    f32x4 ef[4];
#pragma unroll
    for (int s = 0; s < 4; ++s) ef[s] = mfma16(kf[s], qf, f32x4{0.f, 0.f, 0.f, 0.f});

    // ---- prefetch next-step K frags (consumed next iteration)
    const int m1 = (t < 63) ? m0 + 64 : m0;
#pragma unroll
    for (int s = 0; s < 4; ++s)
      kf[s] = *(const u32x4*)(kbase + (size_t)(m1 + 16 * s) * CQ);

    // ---- prefetch this step's V frags (consumed after the barrier)
    u32x4 vf[4];
#pragma unroll
    for (int cs = 0; cs < 2; ++cs)
#pragma unroll
      for (int kc = 0; kc < 2; ++kc)
        vf[2 * cs + kc] = *(const u32x4*)(vbase + (size_t)cs * 16 * NN + m0 + 32 * kc);

    // ---- online softmax (exp2 domain)
    float t0 = fmax3(ef[0][0], ef[0][1], ef[0][2]);
    float t1 = fmax3(ef[0][3], ef[1][0], ef[1][1]);
    float t2 = fmax3(ef[1][2], ef[1][3], ef[2][0]);
    float t3 = fmax3(ef[2][1], ef[2][2], ef[2][3]);
    float t4 = fmax3(ef[3][0], ef[3][1], ef[3][2]);
    float tmax = fmaxf(fmax3(t0, t1, t2), fmax3(t3, t4, ef[3][3]));
    tmax = fmaxf(tmax, __shfl_xor(tmax, 16));
    tmax = fmaxf(tmax, __shfl_xor(tmax, 32));
    const float newm = fmaxf(mrun, tmax);
    const float corr = exp2a(mrun - newm);   // ==1.0 when max unchanged
    float psum = 0.f;
#pragma unroll
    for (int s = 0; s < 4; ++s) {
      const float p0 = exp2a(ef[s][0] - newm);
      const float p1 = exp2a(ef[s][1] - newm);
      const float p2 = exp2a(ef[s][2] - newm);
      const float p3 = exp2a(ef[s][3] - newm);
      psum += (p0 + p1) + (p2 + p3);
      u32x2 pk; pk[0] = cvt_pk(p0, p1); pk[1] = cvt_pk(p2, p3);
      *(u32x2*)&pT[buf][prow][(16 * s + 4 * g) ^ swz] = pk;
    }
    psum += __shfl_xor(psum, 16);
    psum += __shfl_xor(psum, 32);
    lrun = lrun * corr + psum;
    mrun = newm;
    if (lane < 16) corrS[buf][16 * w + lane] = corr;
    __syncthreads();

    // ---- rescale only when some row's max actually grew (rare)
    float cf[4];
#pragma unroll
    for (int ns = 0; ns < 4; ++ns) cf[ns] = corrS[buf][16 * ns + r15];
    const bool need = (cf[0] != 1.f) || (cf[1] != 1.f) || (cf[2] != 1.f) || (cf[3] != 1.f);
    if (__any(need)) {
#pragma unroll
      for (int cs = 0; cs < 2; ++cs)
#pragma unroll
        for (int ns = 0; ns < 4; ++ns) {
          acc[cs][ns][0] *= cf[ns]; acc[cs][ns][1] *= cf[ns];
          acc[cs][ns][2] *= cf[ns]; acc[cs][ns][3] *= cf[ns];
        }
    }

    // ---- PV: acc[cs][ns] += v(A) x P(B)
    __builtin_amdgcn_s_setprio(1);
#pragma unroll
    for (int kc = 0; kc < 2; ++kc) {
      u32x4 pf[4];
#pragma unroll
      for (int ns = 0; ns < 4; ++ns)
        pf[ns] = *(const u32x4*)&pT[buf][16 * ns + r15][(32 * kc + 8 * g) ^ swz];
#pragma unroll
      for (int cs = 0; cs < 2; ++cs) {
#pragma unroll
        for (int ns = 0; ns < 4; ++ns)
          acc[cs][ns] = mfma16(vf[2 * cs + kc], pf[ns], acc[cs][ns]);
      }
    }
    __builtin_amdgcn_s_setprio(0);
  }

  // ---- epilogue: out = gamma * acc/l + F3
  if (lane < 16) lrowS[16 * w + lane] = lrun;
  __syncthreads();
  const float gam = gamma[0];
#pragma unroll
  for (int ns = 0; ns < 4; ++ns) {
    const float inv = 1.f / lrowS[16 * ns + r15];
    const int n = n0 + 16 * ns + r15;
#pragma unroll
    for (int cs = 0; cs < 2; ++cs)
#pragma unroll
      for (int r = 0; r < 4; ++r) {
        const int c = c0w + 16 * cs + 4 * g + r;
        const size_t o = ((size_t)b * CC + c) * NN + n;
        out[o] = fmaf(gam * inv, acc[cs][ns][r], F3[o]);
      }
  }
}

extern "C" void kernel_launch(void* const* d_in, const int* in_sizes, int n_in,
                              void* d_out, int out_size, void* d_ws, size_t ws_size,
                              hipStream_t stream) {
  const float* F3 = (const float*)d_in[0];
  const float* F1 = (const float*)d_in[1];
  const float* F2 = (const float*)d_in[2];
  const float* Wq = (const float*)d_in[3];
  const float* bq = (const float*)d_in[4];
  const float* Wk = (const float*)d_in[5];
  const float* bk = (const float*)d_in[6];
  const float* Wv = (const float*)d_in[7];
  const float* bv = (const float*)d_in[8];
  const float* gm = (const float*)d_in[9];
  float* out = (float*)d_out;

  u16* qT = (u16*)d_ws;                       // 1MB
  u16* kT = qT + (size_t)4 * NN * CQ;         // 1MB
  u16* vW = kT + (size_t)4 * NN * CQ;         // 8MB

  proj_kernel<<<dim3(64, 4, 10), 256, 0, stream>>>(F3, F1, F2, Wq, bq, Wk, bk, Wv, bv, qT, kT, vW);
  attn_kernel<<<512, 256, 0, stream>>>(qT, kT, vW, F3, gm, out);
}

// Round 4
// 217.280 us; speedup vs baseline: 1.6265x; 1.2596x over previous
//
#include <hip/hip_runtime.h>

typedef unsigned short u16;
typedef unsigned int   u32;
typedef __attribute__((ext_vector_type(2))) u32   u32x2;
typedef __attribute__((ext_vector_type(4))) float f32x4;
typedef __attribute__((ext_vector_type(4))) u32   u32x4;
typedef __attribute__((ext_vector_type(8))) short bf16x8;

#define NN 4096
#define CC 256
#define CQ 32

__device__ __forceinline__ u16 f2bf(float x) {
  union { float f; u32 u; } c; c.f = x;
  u32 r = c.u + 0x7FFFu + ((c.u >> 16) & 1u);
  return (u16)(r >> 16);
}

__device__ __forceinline__ u32 cvt_pk(float lo, float hi) {
  u32 r;
  asm("v_cvt_pk_bf16_f32 %0, %1, %2" : "=v"(r) : "v"(lo), "v"(hi));
  return r;
}

#if __has_builtin(__builtin_amdgcn_exp2f)
__device__ __forceinline__ float exp2a(float x) { return __builtin_amdgcn_exp2f(x); }
#else
__device__ __forceinline__ float exp2a(float x) { return exp2f(x); }
#endif

__device__ __forceinline__ float fmax3(float a, float b, float c) {
  return fmaxf(fmaxf(a, b), c);
}

__device__ __forceinline__ f32x4 mfma16(u32x4 a, u32x4 b, f32x4 c) {
  return __builtin_amdgcn_mfma_f32_16x16x32_bf16(
      __builtin_bit_cast(bf16x8, a), __builtin_bit_cast(bf16x8, b), c, 0, 0, 0);
}

// async global->LDS, 16B per lane; LDS dest = uniform base + lane*16
__device__ __forceinline__ void llds16(const u16* g, u16* l) {
  auto gp = (const __attribute__((address_space(1))) u16*)(uintptr_t)g;
  auto lp = (__attribute__((address_space(3))) u16*)(uintptr_t)l;
  __builtin_amdgcn_global_load_lds(gp, lp, 16, 0, 0);
}

// ---------------------------------------------------------------------------
// Kernel 0: convert Wq|Wk|Wv (f32) -> bf16 contiguous blob in ws.
// ---------------------------------------------------------------------------
__global__ __launch_bounds__(256) void wconv(
    const float* __restrict__ Wq, const float* __restrict__ Wk,
    const float* __restrict__ Wv, u16* __restrict__ Wbf) {
  const int i = blockIdx.x * 256 + threadIdx.x;   // 0..81919
  float v;
  if (i < 8192)       v = Wq[i];
  else if (i < 16384) v = Wk[i - 8192];
  else                v = Wv[i - 16384];
  Wbf[i] = f2bf(v);
}

// ---------------------------------------------------------------------------
// Shared proj staging: X tile [256 c][64 n] f32 -> LDS xb[64 n][256 c] bf16,
// granule-XOR swizzled (granule = 8 elems = 16B; slot = (c>>3) ^ (n&7)).
// ---------------------------------------------------------------------------
__device__ __forceinline__ void stage_x(const float* Xb, u16 (*xb)[256], int tid) {
  const int nl = tid & 63;
  const int cg = tid >> 6;
#pragma unroll
  for (int rd = 0; rd < 16; ++rd) {
    const int cb = rd * 16 + cg * 4;
    const float x0 = Xb[(size_t)(cb + 0) * NN];
    const float x1 = Xb[(size_t)(cb + 1) * NN];
    const float x2 = Xb[(size_t)(cb + 2) * NN];
    const float x3 = Xb[(size_t)(cb + 3) * NN];
    u32x2 pk; pk[0] = cvt_pk(x0, x1); pk[1] = cvt_pk(x2, x3);
    const int slot = (cb >> 3) ^ (nl & 7);
    *(u32x2*)&xb[nl][slot * 8 + (cb & 7)] = pk;
  }
}

// ---------------------------------------------------------------------------
// Kernel 1a: q/k projections via MFMA. grid (64 n-tiles, 4 b, 2 z).
// Wave w computes c_out 0..31 for n = n0+16w+{0..15}. Out: qT/kT [b][n][32].
// ---------------------------------------------------------------------------
__global__ __launch_bounds__(256) void proj_qk(
    const float* __restrict__ F3, const float* __restrict__ F1,
    const u16* __restrict__ Wbf,
    const float* __restrict__ bq, const float* __restrict__ bk,
    u16* __restrict__ qT, u16* __restrict__ kT) {
  __shared__ u16 xb[64][256];
  const int n0 = blockIdx.x * 64;
  const int b  = blockIdx.y;
  const int z  = blockIdx.z;
  const float* X = z ? F1 : F3;
  const u16* Wz = Wbf + (z ? 8192 : 0);
  const float* bias = z ? bk : bq;
  const int tid = threadIdx.x;
  stage_x(X + (size_t)b * CC * NN + n0 + (tid & 63), xb, tid);
  __syncthreads();

  const int w = tid >> 6, lane = tid & 63, r15 = lane & 15, g = lane >> 4;
  const int nrow = 16 * w + r15;
  f32x4 acc[2] = {{0.f,0.f,0.f,0.f},{0.f,0.f,0.f,0.f}};
#pragma unroll
  for (int kc = 0; kc < 8; ++kc) {
    const u32x4 bfrg = *(const u32x4*)&xb[nrow][((4 * kc + g) ^ (nrow & 7)) * 8];
#pragma unroll
    for (int s = 0; s < 2; ++s) {
      const u32x4 afrg = *(const u32x4*)(Wz + (size_t)(16 * s + r15) * CC + 32 * kc + 8 * g);
      acc[s] = mfma16(afrg, bfrg, acc[s]);
    }
  }
  const float qsc = z ? 1.0f : (1.4426950408889634f / 5.656854249492380f);
  u16* dst = (z ? kT : qT) + ((size_t)b * NN + n0 + nrow) * CQ;
#pragma unroll
  for (int s = 0; s < 2; ++s) {
    float r0 = (acc[s][0] + bias[16 * s + 4 * g + 0]) * qsc;
    float r1 = (acc[s][1] + bias[16 * s + 4 * g + 1]) * qsc;
    float r2 = (acc[s][2] + bias[16 * s + 4 * g + 2]) * qsc;
    float r3 = (acc[s][3] + bias[16 * s + 4 * g + 3]) * qsc;
    u32x2 o; o[0] = cvt_pk(r0, r1); o[1] = cvt_pk(r2, r3);
    *(u32x2*)(dst + 16 * s + 4 * g) = o;
  }
}

// ---------------------------------------------------------------------------
// Kernel 1b: v projection via MFMA. grid (64 n-tiles, 4 b, 2 c-halves).
// Wave w: 128 c_out for its 16 n. Out: v[b][c][n] bf16 (b16 stores).
// ---------------------------------------------------------------------------
__global__ __launch_bounds__(256) void proj_v(
    const float* __restrict__ F2, const u16* __restrict__ Wbf,
    const float* __restrict__ bv, u16* __restrict__ vO) {
  __shared__ u16 xb[64][256];
  const int n0 = blockIdx.x * 64;
  const int b  = blockIdx.y;
  const int ch = blockIdx.z;           // c-half
  const int tid = threadIdx.x;
  stage_x(F2 + (size_t)b * CC * NN + n0 + (tid & 63), xb, tid);
  __syncthreads();

  const int w = tid >> 6, lane = tid & 63, r15 = lane & 15, g = lane >> 4;
  const int nrow = 16 * w + r15;
  const u16* Wz = Wbf + 16384 + (size_t)ch * 128 * CC;
  f32x4 acc[8];
#pragma unroll
  for (int s = 0; s < 8; ++s) acc[s] = f32x4{0.f, 0.f, 0.f, 0.f};
#pragma unroll
  for (int kc = 0; kc < 8; ++kc) {
    const u32x4 bfrg = *(const u32x4*)&xb[nrow][((4 * kc + g) ^ (nrow & 7)) * 8];
#pragma unroll
    for (int s = 0; s < 8; ++s) {
      const u32x4 afrg = *(const u32x4*)(Wz + (size_t)(16 * s + r15) * CC + 32 * kc + 8 * g);
      acc[s] = mfma16(afrg, bfrg, acc[s]);
    }
  }
  const int n = n0 + nrow;
#pragma unroll
  for (int s = 0; s < 8; ++s)
#pragma unroll
    for (int r = 0; r < 4; ++r) {
      const int c = ch * 128 + 16 * s + 4 * g + r;
      vO[((size_t)b * CC + c) * NN + n] = f2bf(acc[s][r] + bv[c]);
    }
}

// ---------------------------------------------------------------------------
// Kernel 2: flash attention + epilogue. 1024 blocks (4b x 64 n-tiles x 4 cq),
// 4 waves; wave owns 16 n end-to-end (E, softmax, PV) -> P/corr/l wave-
// private. V: 3-buffer LDS ring via global_load_lds (pre-swizzled source),
// ONE raw s_barrier per step with counted vmcnt(6). XCD swizzle pins
// (b, c-pair) per XCD.
// ---------------------------------------------------------------------------
__global__ __launch_bounds__(256, 4) void attn_kernel(
    const u16* __restrict__ qT, const u16* __restrict__ kT, const u16* __restrict__ vV,
    const float* __restrict__ F3, const float* __restrict__ gamma,
    float* __restrict__ out) {
  __shared__ u16 vS[3][64][64];   // 24KB: V tiles [c-local][m-local], swizzled
  __shared__ u16 pP[4][16][64];   // 8KB: per-wave P scratch [n-local][m], swizzled

  const int bid = blockIdx.x;
  const int e = bid & 7, j = bid >> 3;
  const int grp = 2 * e + (j >> 6);     // 0..15 = (b, cq)
  const int i = j & 63;                 // n-tile
  const int b = grp >> 2, cq = grp & 3;
  const int n0 = i * 64, c0 = cq * 64;

  const int tid = threadIdx.x, w = tid >> 6, lane = tid & 63;
  const int r15 = lane & 15, g = lane >> 4;

  const u32x4 qf = *(const u32x4*)(qT + ((size_t)b * NN + n0 + 16 * w + r15) * CQ + 8 * g);
  const u16* kbase = kT + ((size_t)b * NN + r15) * CQ + 8 * g;
  const u16* vbase = vV + ((size_t)b * CC + c0) * NN;

  // staging: wave w stages rows [16w,16w+16), 2 calls of 1KB
  const int srow = (lane >> 3);
  auto stage = [&](int t, int bf) {
#pragma unroll
    for (int qq = 0; qq < 2; ++qq) {
      const int cl = w * 16 + qq * 8 + srow;
      const int gs = (lane & 7) ^ (cl & 7);
      llds16(vbase + (size_t)cl * NN + t * 64 + 8 * gs, &vS[bf][w * 16 + qq * 8][0]);
    }
  };

  stage(0, 0);
  u32x4 kf[4];
#pragma unroll
  for (int s = 0; s < 4; ++s) kf[s] = *(const u32x4*)(kbase + (size_t)(16 * s) * CQ);

  float mrun = -INFINITY, lrun = 0.f;
  f32x4 acc[4];
#pragma unroll
  for (int s = 0; s < 4; ++s) acc[s] = f32x4{0.f, 0.f, 0.f, 0.f};

  int bf = 0;
  for (int t = 0; t < 64; ++t) {
    const int bfn = (bf == 2) ? 0 : bf + 1;
    stage((t + 1) & 63, bfn);                       // 2 vm ops
    const int m1 = ((t + 1) & 63) * 64;
    u32x4 kn[4];
#pragma unroll
    for (int s = 0; s < 4; ++s)                     // 4 vm ops
      kn[s] = *(const u32x4*)(kbase + (size_t)(m1 + 16 * s) * CQ);

    // ---- energy for own 16 n: D[m-local=16s+4g+r][n=r15]
    f32x4 ef[4];
#pragma unroll
    for (int s = 0; s < 4; ++s) ef[s] = mfma16(kf[s], qf, f32x4{0.f, 0.f, 0.f, 0.f});

    // ---- online softmax (exp2 domain; lane-local stats, reduce over g)
    float t0 = fmax3(ef[0][0], ef[0][1], ef[0][2]);
    float t1 = fmax3(ef[0][3], ef[1][0], ef[1][1]);
    float t2 = fmax3(ef[1][2], ef[1][3], ef[2][0]);
    float t3 = fmax3(ef[2][1], ef[2][2], ef[2][3]);
    float t4 = fmax3(ef[3][0], ef[3][1], ef[3][2]);
    float tmax = fmaxf(fmax3(t0, t1, t2), fmax3(t3, t4, ef[3][3]));
    tmax = fmaxf(tmax, __shfl_xor(tmax, 16));
    tmax = fmaxf(tmax, __shfl_xor(tmax, 32));
    const float newm = fmaxf(mrun, tmax);
    const float corr = exp2a(mrun - newm);
    float psum = 0.f;
#pragma unroll
    for (int s = 0; s < 4; ++s) {
      const float p0 = exp2a(ef[s][0] - newm);
      const float p1 = exp2a(ef[s][1] - newm);
      const float p2 = exp2a(ef[s][2] - newm);
      const float p3 = exp2a(ef[s][3] - newm);
      psum += (p0 + p1) + (p2 + p3);
      u32x2 pk; pk[0] = cvt_pk(p0, p1); pk[1] = cvt_pk(p2, p3);
      // granule (2s + (g>>1)) ^ (r15&7), half-granule by g&1
      *(u32x2*)&pP[w][r15][(((2 * s + (g >> 1)) ^ (r15 & 7)) * 8) + (g & 1) * 4] = pk;
    }
    psum += __shfl_xor(psum, 16);
    psum += __shfl_xor(psum, 32);
    lrun = lrun * corr + psum;
    mrun = newm;

    // ---- consume K prefetch late (exp2 section covered the L2 latency)
#pragma unroll
    for (int s = 0; s < 4; ++s) kf[s] = kn[s];

    // ---- wait stage(t) done (6 newer vm ops in flight) + barrier
    asm volatile("s_waitcnt vmcnt(6)\n\ts_barrier" ::: "memory");

    if (__any(corr != 1.0f)) {
#pragma unroll
      for (int s = 0; s < 4; ++s) {
        acc[s][0] *= corr; acc[s][1] *= corr;
        acc[s][2] *= corr; acc[s][3] *= corr;
      }
    }

    // ---- PV: acc[s] += V(A) x P(B) over this 64-m tile
    __builtin_amdgcn_s_setprio(1);
#pragma unroll
    for (int kc = 0; kc < 2; ++kc) {
      const u32x4 pf = *(const u32x4*)&pP[w][r15][((4 * kc + g) ^ (r15 & 7)) * 8];
#pragma unroll
      for (int s = 0; s < 4; ++s) {
        const u32x4 vf = *(const u32x4*)&vS[bf][16 * s + r15][((4 * kc + g) ^ (r15 & 7)) * 8];
        acc[s] = mfma16(vf, pf, acc[s]);
      }
    }
    __builtin_amdgcn_s_setprio(0);
    bf = bfn;
  }

  // ---- epilogue: out = gamma*acc/l + F3 (all lane-local)
  const float sc = gamma[0] / lrun;
  const int n = n0 + 16 * w + r15;
#pragma unroll
  for (int s = 0; s < 4; ++s)
#pragma unroll
    for (int r = 0; r < 4; ++r) {
      const int c = c0 + 16 * s + 4 * g + r;
      const size_t o = ((size_t)b * CC + c) * NN + n;
      out[o] = fmaf(sc, acc[s][r], F3[o]);
    }
}

extern "C" void kernel_launch(void* const* d_in, const int* in_sizes, int n_in,
                              void* d_out, int out_size, void* d_ws, size_t ws_size,
                              hipStream_t stream) {
  const float* F3 = (const float*)d_in[0];
  const float* F1 = (const float*)d_in[1];
  const float* F2 = (const float*)d_in[2];
  const float* Wq = (const float*)d_in[3];
  const float* bq = (const float*)d_in[4];
  const float* Wk = (const float*)d_in[5];
  const float* bk = (const float*)d_in[6];
  const float* Wv = (const float*)d_in[7];
  const float* bv = (const float*)d_in[8];
  const float* gm = (const float*)d_in[9];
  float* out = (float*)d_out;

  u16* qT  = (u16*)d_ws;                        // 1MB
  u16* kT  = qT + (size_t)4 * NN * CQ;          // 1MB
  u16* vW  = kT + (size_t)4 * NN * CQ;          // 8MB
  u16* Wbf = vW + (size_t)4 * CC * NN;          // 160KB

  wconv  <<<320, 256, 0, stream>>>(Wq, Wk, Wv, Wbf);
  proj_qk<<<dim3(64, 4, 2), 256, 0, stream>>>(F3, F1, Wbf, bq, bk, qT, kT);
  proj_v <<<dim3(64, 4, 2), 256, 0, stream>>>(F2, Wbf, bv, vW);
  attn_kernel<<<1024, 256, 0, stream>>>(qT, kT, vW, F3, gm, out);
}

// Round 6
// 205.442 us; speedup vs baseline: 1.7202x; 1.0576x over previous
//
#include <hip/hip_runtime.h>

typedef unsigned short u16;
typedef unsigned int   u32;
typedef __attribute__((ext_vector_type(2))) u32   u32x2;
typedef __attribute__((ext_vector_type(4))) float f32x4;
typedef __attribute__((ext_vector_type(4))) u32   u32x4;
typedef __attribute__((ext_vector_type(8))) short bf16x8;

#define NN 4096
#define CC 256
#define CQ 32

__device__ __forceinline__ u16 f2bf(float x) {
  union { float f; u32 u; } c; c.f = x;
  u32 r = c.u + 0x7FFFu + ((c.u >> 16) & 1u);
  return (u16)(r >> 16);
}

__device__ __forceinline__ u32 cvt_pk(float lo, float hi) {
  u32 r;
  asm("v_cvt_pk_bf16_f32 %0, %1, %2" : "=v"(r) : "v"(lo), "v"(hi));
  return r;
}

#if __has_builtin(__builtin_amdgcn_exp2f)
__device__ __forceinline__ float exp2a(float x) { return __builtin_amdgcn_exp2f(x); }
#else
__device__ __forceinline__ float exp2a(float x) { return exp2f(x); }
#endif

__device__ __forceinline__ float fmax3(float a, float b, float c) {
  return fmaxf(fmaxf(a, b), c);
}

__device__ __forceinline__ f32x4 mfma16(u32x4 a, u32x4 b, f32x4 c) {
  return __builtin_amdgcn_mfma_f32_16x16x32_bf16(
      __builtin_bit_cast(bf16x8, a), __builtin_bit_cast(bf16x8, b), c, 0, 0, 0);
}

// ---------------------------------------------------------------------------
// Kernel 0: convert Wq|Wk|Wv (f32) -> bf16 contiguous blob in ws.
// ---------------------------------------------------------------------------
__global__ __launch_bounds__(256) void wconv(
    const float* __restrict__ Wq, const float* __restrict__ Wk,
    const float* __restrict__ Wv, u16* __restrict__ Wbf) {
  const int i = blockIdx.x * 256 + threadIdx.x;   // 0..81919
  float v;
  if (i < 8192)       v = Wq[i];
  else if (i < 16384) v = Wk[i - 8192];
  else                v = Wv[i - 16384];
  Wbf[i] = f2bf(v);
}

// ---------------------------------------------------------------------------
// Shared proj staging: X tile [256 c][64 n] f32 -> LDS xb[64 n][256 c] bf16.
// Swizzle: granule (16B=8 elems) slot = (c>>3) ^ (n&7) ^ (n>>3).
// The (n>>3) term makes the b64 WRITES conflict-free; reads stay at the
// b128 floor.
// ---------------------------------------------------------------------------
__device__ __forceinline__ void stage_x(const float* Xb, u16 (*xb)[256], int tid) {
  const int nl = tid & 63;
  const int cg = tid >> 6;
#pragma unroll
  for (int rd = 0; rd < 16; ++rd) {
    const int cb = rd * 16 + cg * 4;
    const float x0 = Xb[(size_t)(cb + 0) * NN];
    const float x1 = Xb[(size_t)(cb + 1) * NN];
    const float x2 = Xb[(size_t)(cb + 2) * NN];
    const float x3 = Xb[(size_t)(cb + 3) * NN];
    u32x2 pk; pk[0] = cvt_pk(x0, x1); pk[1] = cvt_pk(x2, x3);
    const int slot = (cb >> 3) ^ (nl & 7) ^ (nl >> 3);
    *(u32x2*)&xb[nl][slot * 8 + (cb & 7)] = pk;
  }
}

// ---------------------------------------------------------------------------
// Kernel 1a: q/k projections via MFMA; all 16 W frags preloaded to registers
// (issued before the stage so L2 latency overlaps), kc loop = pure LDS+MFMA.
// ---------------------------------------------------------------------------
__global__ __launch_bounds__(256) void proj_qk(
    const float* __restrict__ F3, const float* __restrict__ F1,
    const u16* __restrict__ Wbf,
    const float* __restrict__ bq, const float* __restrict__ bk,
    u16* __restrict__ qT, u16* __restrict__ kT) {
  __shared__ u16 xb[64][256];
  const int n0 = blockIdx.x * 64;
  const int b  = blockIdx.y;
  const int z  = blockIdx.z;
  const float* X = z ? F1 : F3;
  const u16* Wz = Wbf + (z ? 8192 : 0);
  const float* bias = z ? bk : bq;
  const int tid = threadIdx.x;
  const int w = tid >> 6, lane = tid & 63, r15 = lane & 15, g = lane >> 4;

  u32x4 wf[8][2];
#pragma unroll
  for (int kc = 0; kc < 8; ++kc)
#pragma unroll
    for (int s = 0; s < 2; ++s)
      wf[kc][s] = *(const u32x4*)(Wz + (size_t)(16 * s + r15) * CC + 32 * kc + 8 * g);

  stage_x(X + (size_t)b * CC * NN + n0 + (tid & 63), xb, tid);
  __syncthreads();

  const int nrow = 16 * w + r15;
  u32x4 bfrg[8];
#pragma unroll
  for (int kc = 0; kc < 8; ++kc)
    bfrg[kc] = *(const u32x4*)&xb[nrow][((4 * kc + g) ^ (nrow & 7) ^ (nrow >> 3)) * 8];

  f32x4 acc[2] = {{0.f,0.f,0.f,0.f},{0.f,0.f,0.f,0.f}};
#pragma unroll
  for (int kc = 0; kc < 8; ++kc)
#pragma unroll
    for (int s = 0; s < 2; ++s)
      acc[s] = mfma16(wf[kc][s], bfrg[kc], acc[s]);

  const float qsc = z ? 1.0f : (1.4426950408889634f / 5.656854249492380f);
  u16* dst = (z ? kT : qT) + ((size_t)b * NN + n0 + nrow) * CQ;
#pragma unroll
  for (int s = 0; s < 2; ++s) {
    float r0 = (acc[s][0] + bias[16 * s + 4 * g + 0]) * qsc;
    float r1 = (acc[s][1] + bias[16 * s + 4 * g + 1]) * qsc;
    float r2 = (acc[s][2] + bias[16 * s + 4 * g + 2]) * qsc;
    float r3 = (acc[s][3] + bias[16 * s + 4 * g + 3]) * qsc;
    u32x2 o; o[0] = cvt_pk(r0, r1); o[1] = cvt_pk(r2, r3);
    *(u32x2*)(dst + 16 * s + 4 * g) = o;
  }
}

// ---------------------------------------------------------------------------
// Kernel 1b: v projection via MFMA; 8 x-frags held in registers, W frags
// software-pipelined by s (prefetch s+1 while mfma'ing s).
// ---------------------------------------------------------------------------
__global__ __launch_bounds__(256) void proj_v(
    const float* __restrict__ F2, const u16* __restrict__ Wbf,
    const float* __restrict__ bv, u16* __restrict__ vO) {
  __shared__ u16 xb[64][256];
  const int n0 = blockIdx.x * 64;
  const int b  = blockIdx.y;
  const int ch = blockIdx.z;
  const int tid = threadIdx.x;
  const int w = tid >> 6, lane = tid & 63, r15 = lane & 15, g = lane >> 4;
  const u16* Wz = Wbf + 16384 + (size_t)ch * 128 * CC;

  u32x4 wfb[2][8];
#pragma unroll
  for (int kc = 0; kc < 8; ++kc)
    wfb[0][kc] = *(const u32x4*)(Wz + (size_t)r15 * CC + 32 * kc + 8 * g);

  stage_x(F2 + (size_t)b * CC * NN + n0 + (tid & 63), xb, tid);
  __syncthreads();

  const int nrow = 16 * w + r15;
  u32x4 bfrg[8];
#pragma unroll
  for (int kc = 0; kc < 8; ++kc)
    bfrg[kc] = *(const u32x4*)&xb[nrow][((4 * kc + g) ^ (nrow & 7) ^ (nrow >> 3)) * 8];

  f32x4 acc[8];
#pragma unroll
  for (int s = 0; s < 8; ++s) acc[s] = f32x4{0.f, 0.f, 0.f, 0.f};
#pragma unroll
  for (int s = 0; s < 8; ++s) {
    if (s < 7) {
#pragma unroll
      for (int kc = 0; kc < 8; ++kc)
        wfb[(s + 1) & 1][kc] =
            *(const u32x4*)(Wz + (size_t)(16 * (s + 1) + r15) * CC + 32 * kc + 8 * g);
    }
#pragma unroll
    for (int kc = 0; kc < 8; ++kc)
      acc[s] = mfma16(wfb[s & 1][kc], bfrg[kc], acc[s]);
  }

  const int n = n0 + nrow;
#pragma unroll
  for (int s = 0; s < 8; ++s)
#pragma unroll
    for (int r = 0; r < 4; ++r) {
      const int c = ch * 128 + 16 * s + 4 * g + r;
      vO[((size_t)b * CC + c) * NN + n] = f2bf(acc[s][r] + bv[c]);
    }
}

// ---------------------------------------------------------------------------
// Kernel 2: flash attention + epilogue, NO softmax duplication.
// 256 blocks (1/CU) x 512 thr = 8 waves. Block = 64 n x 256 c (full row).
// Wave w: (p = w>>2) = m-half for E/softmax of n-group (ng = w&3);
// PV for its private c-slice 32c x all 64 n (acc[2][4], V direct from L2).
// Per step: E(2 mfma) -> half-max -> [bar1] -> merge max, exp own half,
// P -> shared LDS (dbuf) -> [bar2] -> rescale + PV(16 mfma).
// Raw s_barrier + lgkmcnt(0) only: K/V prefetches stay in flight across
// barriers. Unroll-by-2 gives static prefetch double-buffers.
// ---------------------------------------------------------------------------
__global__ __launch_bounds__(512, 2) void attn_kernel(
    const u16* __restrict__ qT, const u16* __restrict__ kT, const u16* __restrict__ vV,
    const float* __restrict__ F3, const float* __restrict__ gamma,
    float* __restrict__ out) {
  __shared__ u16   pP[2][4][16][64];   // 16KB: [dbuf][ng][n=r15][m], swizzled
  __shared__ float corrS[2][4][16];
  __shared__ float maxS[4][16][2];     // [ng][n][p] half-max exchange
  __shared__ float lS[4][16][2];

  const int bid = blockIdx.x;
  const int xcd = bid & 7, i0 = bid >> 3;
  const int b  = xcd >> 1;                       // batch pinned to XCD pair
  const int n0 = ((((xcd & 1) << 5) | i0)) * 64; // n-tile

  const int tid = threadIdx.x, w = tid >> 6, lane = tid & 63;
  const int r15 = lane & 15, g = lane >> 4;
  const int p = w >> 2, ng = w & 3;

  const u32x4 qf = *(const u32x4*)(qT + ((size_t)b * NN + n0 + 16 * ng + r15) * CQ + 8 * g);
  const u16* klane = kT + ((size_t)b * NN + 32 * p + r15) * CQ + 8 * g;
  const u16* vlane = vV + ((size_t)b * CC + 32 * w + r15) * NN + 8 * g;

  f32x4 acc[2][4];
#pragma unroll
  for (int ct = 0; ct < 2; ++ct)
#pragma unroll
    for (int j = 0; j < 4; ++j) acc[ct][j] = f32x4{0.f, 0.f, 0.f, 0.f};
  float mrun = -INFINITY, lrun = 0.f;

  u32x4 kA[2], kB[2], vA[4], vB[4];
#pragma unroll
  for (int s = 0; s < 2; ++s) kA[s] = *(const u32x4*)(klane + 16 * s * CQ);
#pragma unroll
  for (int ct = 0; ct < 2; ++ct)
#pragma unroll
    for (int kc = 0; kc < 2; ++kc)
      vA[2 * ct + kc] = *(const u32x4*)(vlane + (size_t)ct * 16 * NN + 32 * kc);

#define STEP(T, BUF, KU, KP, VU, VP)                                           \
  {                                                                            \
    const int tn = ((T) + 1 < 64) ? (T) + 1 : (T);                             \
    const int mo = tn * 64;                                                    \
    _Pragma("unroll")                                                          \
    for (int s = 0; s < 2; ++s)                                                \
      KP[s] = *(const u32x4*)(klane + (mo + 16 * s) * CQ);                     \
    _Pragma("unroll")                                                          \
    for (int ct = 0; ct < 2; ++ct)                                             \
      _Pragma("unroll")                                                        \
      for (int kc = 0; kc < 2; ++kc)                                           \
        VP[2 * ct + kc] =                                                      \
            *(const u32x4*)(vlane + (size_t)ct * 16 * NN + mo + 32 * kc);      \
    f32x4 ef0 = mfma16(KU[0], qf, f32x4{0.f, 0.f, 0.f, 0.f});                  \
    f32x4 ef1 = mfma16(KU[1], qf, f32x4{0.f, 0.f, 0.f, 0.f});                  \
    float hmax = fmax3(fmax3(ef0[0], ef0[1], ef0[2]),                          \
                       fmax3(ef0[3], ef1[0], ef1[1]),                          \
                       fmaxf(ef1[2], ef1[3]));                                 \
    hmax = fmaxf(hmax, __shfl_xor(hmax, 16));                                  \
    hmax = fmaxf(hmax, __shfl_xor(hmax, 32));                                  \
    if (lane < 16) maxS[ng][lane][p] = hmax;                                   \
    asm volatile("s_waitcnt lgkmcnt(0)\n\ts_barrier" ::: "memory");            \
    const float om = maxS[ng][r15][1 - p];                                     \
    const float newm = fmaxf(mrun, fmaxf(hmax, om));                           \
    const float corr = exp2a(mrun - newm);                                     \
    mrun = newm;                                                               \
    const float q0 = exp2a(ef0[0] - newm), q1 = exp2a(ef0[1] - newm);          \
    const float q2 = exp2a(ef0[2] - newm), q3 = exp2a(ef0[3] - newm);          \
    const float q4 = exp2a(ef1[0] - newm), q5 = exp2a(ef1[1] - newm);          \
    const float q6 = exp2a(ef1[2] - newm), q7 = exp2a(ef1[3] - newm);          \
    float ps = ((q0 + q1) + (q2 + q3)) + ((q4 + q5) + (q6 + q7));              \
    ps += __shfl_xor(ps, 16);                                                  \
    ps += __shfl_xor(ps, 32);                                                  \
    lrun = lrun * corr + ps;                                                   \
    {                                                                          \
      u32x2 pk0; pk0[0] = cvt_pk(q0, q1); pk0[1] = cvt_pk(q2, q3);             \
      const int sl0 = (4 * p + (g >> 1)) ^ (r15 & 7);                          \
      *(u32x2*)&pP[BUF][ng][r15][sl0 * 8 + (g & 1) * 4] = pk0;                 \
      u32x2 pk1; pk1[0] = cvt_pk(q4, q5); pk1[1] = cvt_pk(q6, q7);             \
      const int sl1 = (4 * p + 2 + (g >> 1)) ^ (r15 & 7);                      \
      *(u32x2*)&pP[BUF][ng][r15][sl1 * 8 + (g & 1) * 4] = pk1;                 \
    }                                                                          \
    if (lane < 16) corrS[BUF][ng][lane] = corr;                                \
    asm volatile("s_waitcnt lgkmcnt(0)\n\ts_barrier" ::: "memory");            \
    float cf[4];                                                               \
    _Pragma("unroll")                                                          \
    for (int j = 0; j < 4; ++j) cf[j] = corrS[BUF][j][r15];                    \
    if (__any((cf[0] != 1.f) | (cf[1] != 1.f) | (cf[2] != 1.f) |               \
              (cf[3] != 1.f))) {                                               \
      _Pragma("unroll")                                                        \
      for (int ct = 0; ct < 2; ++ct)                                           \
        _Pragma("unroll")                                                      \
        for (int j = 0; j < 4; ++j) {                                          \
          acc[ct][j][0] *= cf[j]; acc[ct][j][1] *= cf[j];                      \
          acc[ct][j][2] *= cf[j]; acc[ct][j][3] *= cf[j];                      \
        }                                                                      \
    }                                                                          \
    __builtin_amdgcn_s_setprio(1);                                             \
    _Pragma("unroll")                                                          \
    for (int kc = 0; kc < 2; ++kc) {                                           \
      u32x4 pf[4];                                                             \
      _Pragma("unroll")                                                        \
      for (int j = 0; j < 4; ++j)                                              \
        pf[j] = *(const u32x4*)&pP[BUF][j][r15][((4 * kc + g) ^ (r15 & 7)) * 8]; \
      _Pragma("unroll")                                                        \
      for (int ct = 0; ct < 2; ++ct)                                           \
        _Pragma("unroll")                                                      \
        for (int j = 0; j < 4; ++j)                                            \
          acc[ct][j] = mfma16(VU[2 * ct + kc], pf[j], acc[ct][j]);             \
    }                                                                          \
    __builtin_amdgcn_s_setprio(0);                                             \
  }

  for (int t = 0; t < 64; t += 2) {
    STEP(t,     0, kA, kB, vA, vB)
    STEP(t + 1, 1, kB, kA, vB, vA)
  }
#undef STEP

  // ---- merge half-l's, epilogue: out = gamma*acc/l + F3
  if (lane < 16) lS[ng][lane][p] = lrun;
  __syncthreads();
  const float gam = gamma[0];
  float linv[4];
#pragma unroll
  for (int j = 0; j < 4; ++j) linv[j] = gam / (lS[j][r15][0] + lS[j][r15][1]);
#pragma unroll
  for (int ct = 0; ct < 2; ++ct)
#pragma unroll
    for (int j = 0; j < 4; ++j)
#pragma unroll
      for (int r = 0; r < 4; ++r) {
        const int c = 32 * w + 16 * ct + 4 * g + r;
        const int n = n0 + 16 * j + r15;
        const size_t o = ((size_t)b * CC + c) * NN + n;
        out[o] = fmaf(linv[j], acc[ct][j][r], F3[o]);
      }
}

extern "C" void kernel_launch(void* const* d_in, const int* in_sizes, int n_in,
                              void* d_out, int out_size, void* d_ws, size_t ws_size,
                              hipStream_t stream) {
  const float* F3 = (const float*)d_in[0];
  const float* F1 = (const float*)d_in[1];
  const float* F2 = (const float*)d_in[2];
  const float* Wq = (const float*)d_in[3];
  const float* bq = (const float*)d_in[4];
  const float* Wk = (const float*)d_in[5];
  const float* bk = (const float*)d_in[6];
  const float* Wv = (const float*)d_in[7];
  const float* bv = (const float*)d_in[8];
  const float* gm = (const float*)d_in[9];
  float* out = (float*)d_out;

  u16* qT  = (u16*)d_ws;                        // 1MB
  u16* kT  = qT + (size_t)4 * NN * CQ;          // 1MB
  u16* vW  = kT + (size_t)4 * NN * CQ;          // 8MB
  u16* Wbf = vW + (size_t)4 * CC * NN;          // 160KB

  wconv  <<<320, 256, 0, stream>>>(Wq, Wk, Wv, Wbf);
  proj_qk<<<dim3(64, 4, 2), 256, 0, stream>>>(F3, F1, Wbf, bq, bk, qT, kT);
  proj_v <<<dim3(64, 4, 2), 256, 0, stream>>>(F2, Wbf, bv, vW);
  attn_kernel<<<256, 512, 0, stream>>>(qT, kT, vW, F3, gm, out);
}